// Round 3
// baseline (6059.804 us; speedup 1.0000x reference)
//
#include <hip/hip_runtime.h>
#include <hip/hip_bf16.h>

// Bidirectional LSTM, B=32 T=512 D=512 U=512, fp32 in/out, bf16 MFMA internals.
// Phase 1: xg = x @ [Wf||Wb] + b  (bf16 MFMA GEMM, permuted columns)
// Phase 2: persistent recurrence, 32 groups/direction, U^T in registers.
//          R7: swapped-operand MFMA (D = U^T·h) so each lane holds all 4 gates
//          of one unit lane-locally -> no gate transpose. h exchange as 8B
//          {bf16 h[b], bf16 h[b+16], u32 step} records at Infinity Cache
//          (data IS the flag). R5-style conflict-free LDS chunk-XOR swizzle.
//          Double-buffered h_lds -> ONE barrier per step. Selective poll retry.
// Phase 3: out = fwd + bwd

typedef __attribute__((ext_vector_type(8))) __bf16 bf16x8;
typedef __attribute__((ext_vector_type(4))) __bf16 bf16x4;
typedef __attribute__((ext_vector_type(4))) float fvec4;
typedef __attribute__((ext_vector_type(4))) unsigned int uvec4;

#define AS_G(p) ((const __attribute__((address_space(1))) void*)(p))
#define AS_L(p) ((__attribute__((address_space(3))) void*)(p))

__device__ __forceinline__ float sigm(float x) {
  return __builtin_amdgcn_rcpf(1.f + __expf(-x));
}
__device__ __forceinline__ float tanh_f(float x) {
  return 1.f - 2.f * __builtin_amdgcn_rcpf(__expf(2.f * x) + 1.f);
}

// ---------------- conversions ----------------

__global__ void k_convert_x(const float* __restrict__ x, __bf16* __restrict__ xb) {
  size_t i = ((size_t)blockIdx.x * 256 + threadIdx.x) * 8;
  fvec4 a = *(const fvec4*)(x + i);
  fvec4 b = *(const fvec4*)(x + i + 4);
  bf16x8 o;
#pragma unroll
  for (int j = 0; j < 4; ++j) { o[j] = (__bf16)a[j]; o[4 + j] = (__bf16)b[j]; }
  *(bf16x8*)(xb + i) = o;
}

// dst[p][k] = src[k][orig(p)] as bf16. Permutation: p = g*64 + w*16 + jj*4 + gate
// <-> orig = gate*512 + g*16 + w*4 + jj  (Keras gate order i,f,c,o).
__global__ void k_build_T(const float* __restrict__ src, const float* __restrict__ bvec,
                          __bf16* __restrict__ dst, float* __restrict__ bias_out) {
  int p = blockIdx.x;
  int g = p >> 6, r = p & 63, w = r >> 4, q = r & 15, jj = q >> 2, gate = q & 3;
  int orig = gate * 512 + g * 16 + w * 4 + jj;
  for (int k = threadIdx.x; k < 512; k += 256)
    dst[(size_t)p * 512 + k] = (__bf16)src[(size_t)k * 2048 + orig];
  if (bias_out && threadIdx.x == 0) bias_out[p] = bvec[orig];
}

// init h records: [dir 2][par 2][b16 16][u 512] of 8B {h[b16], h[b16+16], step}.
// parity 0 holds h(0)=z with step counter 0; parity 1 zeroed (counter 0 never
// matches an odd step, so consumers of step 1 wait for the real publish).
__global__ void k_init_rec(const float* __restrict__ z,
                           unsigned long long* __restrict__ rbuf) {
  int idx = blockIdx.x * 256 + threadIdx.x;      // 0..32767
  int par = (idx >> 13) & 1;
  int e = idx & 8191, b16 = e >> 9, u = e & 511;
  unsigned long long v = 0ull;
  if (par == 0) {
    union { __bf16 h[2]; unsigned u32; } pk;
    pk.h[0] = (__bf16)z[b16 * 512 + u];
    pk.h[1] = (__bf16)z[(b16 + 16) * 512 + u];
    v = (unsigned long long)pk.u32;              // counter 0 in high word
  }
  rbuf[idx] = v;
}

// ---------------- input GEMM: [16384,512] x [4096,512]^T -> bf16 [16384,4096] ----------------

__global__ __launch_bounds__(256, 2) void k_gemm_xw(
    const __bf16* __restrict__ A,   // [16384][512] bf16
    const __bf16* __restrict__ Bt,  // [4096][512] bf16 (permuted W^T)
    const float* __restrict__ bias, // [4096] permuted
    __bf16* __restrict__ C)         // [16384][4096]
{
  __shared__ __align__(16) __bf16 As[128 * 32];
  __shared__ __align__(16) __bf16 Bs[128 * 32];
  const int tid = threadIdx.x;
  const int w = tid >> 6, lane = tid & 63, quad = lane >> 4, l15 = lane & 15;
  const int m0 = blockIdx.y * 128, n0 = blockIdx.x * 128;
  const int wm = w & 1, wn = w >> 1;

  fvec4 acc[4][4];
  const fvec4 zero = {0.f, 0.f, 0.f, 0.f};
#pragma unroll
  for (int i = 0; i < 4; ++i)
#pragma unroll
    for (int j = 0; j < 4; ++j) acc[i][j] = zero;

  for (int kb = 0; kb < 16; ++kb) {
    const int k0 = kb * 32;
#pragma unroll
    for (int i = 0; i < 2; ++i) {
      const int c = (i * 4 + w) * 64 + lane;      // 16B chunk id, 0..511
      const int row = c >> 2, kk = (c & 3) * 8;
      __builtin_amdgcn_global_load_lds(AS_G(A + (size_t)(m0 + row) * 512 + k0 + kk),
                                       AS_L(As + (size_t)(i * 4 + w) * 512), 16, 0, 0);
      __builtin_amdgcn_global_load_lds(AS_G(Bt + (size_t)(n0 + row) * 512 + k0 + kk),
                                       AS_L(Bs + (size_t)(i * 4 + w) * 512), 16, 0, 0);
    }
    __syncthreads();
    bf16x8 af[4], bfr[4];
#pragma unroll
    for (int mt = 0; mt < 4; ++mt)
      af[mt] = *(const bf16x8*)(As + (wm * 64 + mt * 16 + l15) * 32 + quad * 8);
#pragma unroll
    for (int nt = 0; nt < 4; ++nt)
      bfr[nt] = *(const bf16x8*)(Bs + (wn * 64 + nt * 16 + l15) * 32 + quad * 8);
#pragma unroll
    for (int mt = 0; mt < 4; ++mt)
#pragma unroll
      for (int nt = 0; nt < 4; ++nt)
        acc[mt][nt] = __builtin_amdgcn_mfma_f32_16x16x32_bf16(af[mt], bfr[nt], acc[mt][nt], 0, 0, 0);
    __syncthreads();
  }

#pragma unroll
  for (int nt = 0; nt < 4; ++nt) {
    const int col = n0 + wn * 64 + nt * 16 + l15;
    const float bv = bias[col];
#pragma unroll
    for (int mt = 0; mt < 4; ++mt) {
      const int rowb = m0 + wm * 64 + mt * 16 + quad * 4;
#pragma unroll
      for (int r = 0; r < 4; ++r)
        C[(size_t)(rowb + r) * 4096 + col] = (__bf16)(acc[mt][nt][r] + bv);
    }
  }
}

// ---------------- persistent recurrence ----------------
// 64 blocks: dir = blk>>5, group g = blk&31 owns units u in [g*16, g*16+16).
// Lane (w, quad, l15): unit u = g*16 + w*4 + quad, batches b = l15 and l15+16.
// MFMA (swapped): D = A(U^T rows = gatecols jj*4+gate) x B(h cols = b)
//   -> lane (quad,l15) gets acc[reg] = gate 'reg' of unit jj=quad, b=l15 (acc0)
//   and b=l15+16 (acc1): gates are lane-local, NO transpose.
// rbuf records [dir][par][b16][u]: {h[b16][u], h[b16+16][u], step} as one 8B
//   single-copy-atomic store -> step counter certifies the payload.
// Poll safety: producer publishes kt+1 only after its poll of kt passed, which
//   requires all blocks' poll-loads of the records it overwrites to have
//   completed. '== kt' matches exactly the wanted generation.
// h_lds[2] double buffer: step kt uses buffer kt&1; WAR on reuse (kt vs kt+2)
//   is separated by step kt+1's barrier -> ONE barrier per step.
// Swizzle (R5-proven): 16B chunk index XOR (row>>1)&3 -> staging b128 writes
//   and fragment b128 reads are conflict-free per 16-lane quarter-wave.

__global__ __launch_bounds__(256, 1) void k_lstm_rec(
    const __bf16* __restrict__ xg,            // [16384][4096] permuted
    const float* __restrict__ z,              // [32][512]
    const __bf16* __restrict__ UT,            // [2][2048][512] permuted
    unsigned long long* __restrict__ rbuf,    // [2][2][8192] records
    float* __restrict__ outf,                 // d_out [32][512][512] (fwd)
    __bf16* __restrict__ outb)                // ws [32][512][512] (bwd)
{
  const int blk = blockIdx.x, dir = blk >> 5, g = blk & 31;
  const int tid = threadIdx.x, w = tid >> 6, lane = tid & 63;
  const int quad = lane >> 4, l15 = lane & 15;
  __shared__ __align__(16) char h_lds[2][16 * 2048];   // 64 KB double buffer

  // U^T slice resident in registers for all 512 steps (64 VGPRs)
  bf16x8 breg[16];
  {
    const __bf16* up = UT + ((size_t)dir * 2048 + g * 64 + w * 16 + l15) * 512 + quad * 8;
#pragma unroll
    for (int ks = 0; ks < 16; ++ks) breg[ks] = *(const bf16x8*)(up + ks * 32);
  }

  const int u = g * 16 + w * 4 + quad;
  float c0 = z[l15 * 512 + u];
  float c1 = z[(l15 + 16) * 512 + u];

  // staging role: thread (ks_s = w*4+quad, b16 = l15) owns the 32 contiguous
  // records [b16][ks_s*32 .. ks_s*32+32) = full ks-slice for its two rows.
  const int ks_s = w * 4 + quad;
  const int swz = (l15 >> 1) & 3;
  unsigned long long* rb_dir = rbuf + (size_t)dir * 16384;
  const unsigned long long* src_base = rb_dir + l15 * 512 + ks_s * 32;
  const int pidx = l15 * 512 + u;
  const size_t xgoff = (size_t)dir * 2048 + g * 64 + w * 16 + quad * 4;

  for (int kt = 0; kt < 512; ++kt) {
    const int t = dir ? (511 - kt) : kt;
    const int pr = kt & 1;

    // xg prefetch (independent; completes under the poll)
    const bf16x4 xA = *(const bf16x4*)(xg + (size_t)(l15 * 512 + t) * 4096 + xgoff);
    const bf16x4 xB = *(const bf16x4*)(xg + (size_t)((l15 + 16) * 512 + t) * 4096 + xgoff);

    // ---- poll-on-data: 32 x 8B contiguous records; selective retry ----
    unsigned long long rec[32];
    {
      const unsigned long long* srcp = src_base + pr * 8192;
      const unsigned expect = (unsigned)kt;
      int need = 1;
      for (;;) {
        if (need) {
#pragma unroll
          for (int it = 0; it < 32; ++it)
            rec[it] = __hip_atomic_load(srcp + it, __ATOMIC_RELAXED,
                                        __HIP_MEMORY_SCOPE_AGENT);
          int ok = 1;
#pragma unroll
          for (int it = 0; it < 32; ++it)
            ok &= ((unsigned)(rec[it] >> 32) == expect);
          need = !ok;
        }
        if (!__ballot(need)) break;
        __builtin_amdgcn_s_sleep(1);
      }
    }

    // ---- pack payloads & stage into buffer pr (conflict-free b128 writes) ----
    {
      char* base = h_lds[pr] + ks_s * 2048 + l15 * 64;
#pragma unroll
      for (int cu = 0; cu < 4; ++cu) {
        uvec4 lo, hi;
#pragma unroll
        for (int i = 0; i < 4; ++i) {
          const unsigned p0 = (unsigned)rec[cu * 8 + 2 * i];
          const unsigned p1 = (unsigned)rec[cu * 8 + 2 * i + 1];
          lo[i] = (p0 & 0xffffu) | (p1 << 16);
          hi[i] = (p0 >> 16) | (p1 & 0xffff0000u);
        }
        const int cpos = ((cu ^ swz) * 16);
        *(uvec4*)(base + cpos) = lo;           // row b16
        *(uvec4*)(base + 1024 + cpos) = hi;    // row b16+16
      }
    }
    // single barrier per step: staging visible; also separates frag reads of
    // step kt-2 from this buffer's reuse (double buffer covers kt-1).
    asm volatile("s_waitcnt lgkmcnt(0)\n\ts_barrier" ::: "memory");

    fvec4 acc0 = {0.f, 0.f, 0.f, 0.f}, acc1 = {0.f, 0.f, 0.f, 0.f};
    {
      const char* rbase = h_lds[pr];
#pragma unroll 8
      for (int ks = 0; ks < 16; ++ks) {
        const char* p = rbase + ks * 2048 + l15 * 64 + ((quad ^ swz) * 16);
        bf16x8 a0 = *(const bf16x8*)p;
        bf16x8 a1 = *(const bf16x8*)(p + 1024);
        acc0 = __builtin_amdgcn_mfma_f32_16x16x32_bf16(breg[ks], a0, acc0, 0, 0, 0);
        acc1 = __builtin_amdgcn_mfma_f32_16x16x32_bf16(breg[ks], a1, acc1, 0, 0, 0);
      }
    }

    // gates are lane-local: acc[reg] = gate reg (i,f,c,o) for this lane's unit
    float ii = sigm(acc0[0] + (float)xA[0]);
    float ff = sigm(acc0[1] + (float)xA[1]);
    float cc = tanh_f(acc0[2] + (float)xA[2]);
    float oo = sigm(acc0[3] + (float)xA[3]);
    c0 = ff * c0 + ii * cc;
    const float h0 = oo * tanh_f(c0);

    ii = sigm(acc1[0] + (float)xB[0]);
    ff = sigm(acc1[1] + (float)xB[1]);
    cc = tanh_f(acc1[2] + (float)xB[2]);
    oo = sigm(acc1[3] + (float)xB[3]);
    c1 = ff * c1 + ii * cc;
    const float h1 = oo * tanh_f(c1);

    // fire-and-forget publish: {h0,h1,kt+1} in one single-copy-atomic 8B record
    union { __bf16 h[2]; unsigned u32; } pk;
    pk.h[0] = (__bf16)h0;
    pk.h[1] = (__bf16)h1;
    const unsigned long long rv =
        (unsigned long long)pk.u32 | ((unsigned long long)(unsigned)(kt + 1) << 32);
    __hip_atomic_store(rb_dir + ((kt + 1) & 1) * 8192 + pidx, rv,
                       __ATOMIC_RELAXED, __HIP_MEMORY_SCOPE_AGENT);

    // out stores off the critical path (acked well before next poll's wait)
    const size_t o0 = (size_t)(l15 * 512 + t) * 512 + u;
    const size_t o1 = (size_t)((l15 + 16) * 512 + t) * 512 + u;
    if (dir == 0) {
      outf[o0] = h0;
      outf[o1] = h1;
    } else {
      outb[o0] = (__bf16)h0;
      outb[o1] = (__bf16)h1;
    }
  }
}

// ---------------- final merge ----------------

__global__ void k_add_bwd(float* __restrict__ out, const __bf16* __restrict__ outb) {
  size_t i = ((size_t)blockIdx.x * 256 + threadIdx.x) * 4;
  if (i >= (size_t)32 * 512 * 512) return;
  fvec4 o = *(const fvec4*)(out + i);
  bf16x4 bv = *(const bf16x4*)(outb + i);
#pragma unroll
  for (int j = 0; j < 4; ++j) o[j] += (float)bv[j];
  *(fvec4*)(out + i) = o;
}

// ---------------- host ----------------

extern "C" void kernel_launch(void* const* d_in, const int* in_sizes, int n_in,
                              void* d_out, int out_size, void* d_ws, size_t ws_size,
                              hipStream_t stream) {
  const float* x  = (const float*)d_in[0];
  const float* z  = (const float*)d_in[1];
  const float* Wf = (const float*)d_in[2];
  const float* Uf = (const float*)d_in[3];
  const float* bf = (const float*)d_in[4];
  const float* Wb = (const float*)d_in[5];
  const float* Ub = (const float*)d_in[6];
  const float* bb = (const float*)d_in[7];
  float* out = (float*)d_out;
  char* ws = (char*)d_ws;

  size_t off = 0;
  __bf16* xg = (__bf16*)(ws + off); off += (size_t)16384 * 4096 * 2;   // 134 MB
  __bf16* UT = (__bf16*)(ws + off); off += (size_t)2 * 2048 * 512 * 2; // 4 MB
  unsigned long long* rbuf = (unsigned long long*)(ws + off);
  off += (size_t)2 * 2 * 8192 * 8;                                     // 256 KB
  float* biasp = (float*)(ws + off); off += 4096 * 4;
  char* uni = ws + off;
  __bf16* xb   = (__bf16*)uni;                               // phase 1
  __bf16* WT   = (__bf16*)(uni + (size_t)16384 * 512 * 2);   // phase 1
  __bf16* outb = (__bf16*)uni;                               // phase 2 (aliases xb)

  k_convert_x<<<4096, 256, 0, stream>>>(x, xb);
  k_build_T<<<2048, 256, 0, stream>>>(Wf, bf, WT, biasp);
  k_build_T<<<2048, 256, 0, stream>>>(Wb, bb, WT + (size_t)2048 * 512, biasp + 2048);
  k_build_T<<<2048, 256, 0, stream>>>(Uf, nullptr, UT, nullptr);
  k_build_T<<<2048, 256, 0, stream>>>(Ub, nullptr, UT + (size_t)2048 * 512, nullptr);
  k_init_rec<<<128, 256, 0, stream>>>(z, rbuf);
  k_gemm_xw<<<dim3(32, 128), 256, 0, stream>>>(xb, WT, biasp, xg);
  k_lstm_rec<<<64, 256, 0, stream>>>(xg, z, UT, rbuf, out, outb);
  k_add_bwd<<<8192, 256, 0, stream>>>(out, outb);
}

// Round 4
// 4378.975 us; speedup vs baseline: 1.3838x; 1.3838x over previous
//
#include <hip/hip_runtime.h>
#include <hip/hip_bf16.h>

// Bidirectional LSTM, B=32 T=512 D=512 U=512, fp32 in/out, bf16 MFMA internals.
// Phase 1: xg = x @ [Wf||Wb] + b  (bf16 MFMA GEMM, permuted columns)
// Phase 2: persistent recurrence, 32 groups/direction, U^T in registers.
//          R8 = R5 sync skeleton + R7 compute core:
//          - wave0 polls 32 mailbox flags (tiny, cheap); bulk h loaded ONCE
//          - records are self-certifying {bf16 h0, bf16 h1, u32 step} 8B stores
//            -> NO vmcnt(0) store-ack drain before flagging (saves 1 RT/step);
//            counter-verify with rare retry catches record/flag races
//          - swapped-operand MFMA: gates lane-local (no transpose LDS round trip)
//          - R7 chunk-XOR LDS swizzle: 0 bank conflicts (verified)
// Phase 3: out = fwd + bwd

typedef __attribute__((ext_vector_type(8))) __bf16 bf16x8;
typedef __attribute__((ext_vector_type(4))) __bf16 bf16x4;
typedef __attribute__((ext_vector_type(4))) float fvec4;
typedef __attribute__((ext_vector_type(4))) unsigned int uvec4;

#define AS_G(p) ((const __attribute__((address_space(1))) void*)(p))
#define AS_L(p) ((__attribute__((address_space(3))) void*)(p))

__device__ __forceinline__ float sigm(float x) {
  return __builtin_amdgcn_rcpf(1.f + __expf(-x));
}
__device__ __forceinline__ float tanh_f(float x) {
  return 1.f - 2.f * __builtin_amdgcn_rcpf(__expf(2.f * x) + 1.f);
}

// ---------------- conversions ----------------

__global__ void k_convert_x(const float* __restrict__ x, __bf16* __restrict__ xb) {
  size_t i = ((size_t)blockIdx.x * 256 + threadIdx.x) * 8;
  fvec4 a = *(const fvec4*)(x + i);
  fvec4 b = *(const fvec4*)(x + i + 4);
  bf16x8 o;
#pragma unroll
  for (int j = 0; j < 4; ++j) { o[j] = (__bf16)a[j]; o[4 + j] = (__bf16)b[j]; }
  *(bf16x8*)(xb + i) = o;
}

// dst[p][k] = src[k][orig(p)] as bf16. Permutation: p = g*64 + w*16 + jj*4 + gate
// <-> orig = gate*512 + g*16 + w*4 + jj  (Keras gate order i,f,c,o).
__global__ void k_build_T(const float* __restrict__ src, const float* __restrict__ bvec,
                          __bf16* __restrict__ dst, float* __restrict__ bias_out) {
  int p = blockIdx.x;
  int g = p >> 6, r = p & 63, w = r >> 4, q = r & 15, jj = q >> 2, gate = q & 3;
  int orig = gate * 512 + g * 16 + w * 4 + jj;
  for (int k = threadIdx.x; k < 512; k += 256)
    dst[(size_t)p * 512 + k] = (__bf16)src[(size_t)k * 2048 + orig];
  if (bias_out && threadIdx.x == 0) bias_out[p] = bvec[orig];
}

// init h records: [dir 2][par 2][b16 16][u 512] of 8B {h[b16], h[b16+16], step}.
// parity 0 holds h(0)=z with step counter 0; parity 1 zeroed.
__global__ void k_init_rec(const float* __restrict__ z,
                           unsigned long long* __restrict__ rbuf) {
  int idx = blockIdx.x * 256 + threadIdx.x;      // 0..32767
  int par = (idx >> 13) & 1;
  int e = idx & 8191, b16 = e >> 9, u = e & 511;
  unsigned long long v = 0ull;
  if (par == 0) {
    union { __bf16 h[2]; unsigned u32; } pk;
    pk.h[0] = (__bf16)z[b16 * 512 + u];
    pk.h[1] = (__bf16)z[(b16 + 16) * 512 + u];
    v = (unsigned long long)pk.u32;              // counter 0 in high word
  }
  rbuf[idx] = v;
}

// zero the mailbox region: 2 dirs * 32 consumers * 32 producers ints
__global__ void k_init_flags(int* mbox) {
  int i = blockIdx.x * 256 + threadIdx.x;
  if (i < 2048) mbox[i] = 0;
}

// ---------------- input GEMM: [16384,512] x [4096,512]^T -> bf16 [16384,4096] ----------------

__global__ __launch_bounds__(256, 2) void k_gemm_xw(
    const __bf16* __restrict__ A,   // [16384][512] bf16
    const __bf16* __restrict__ Bt,  // [4096][512] bf16 (permuted W^T)
    const float* __restrict__ bias, // [4096] permuted
    __bf16* __restrict__ C)         // [16384][4096]
{
  __shared__ __align__(16) __bf16 As[128 * 32];
  __shared__ __align__(16) __bf16 Bs[128 * 32];
  const int tid = threadIdx.x;
  const int w = tid >> 6, lane = tid & 63, quad = lane >> 4, l15 = lane & 15;
  const int m0 = blockIdx.y * 128, n0 = blockIdx.x * 128;
  const int wm = w & 1, wn = w >> 1;

  fvec4 acc[4][4];
  const fvec4 zero = {0.f, 0.f, 0.f, 0.f};
#pragma unroll
  for (int i = 0; i < 4; ++i)
#pragma unroll
    for (int j = 0; j < 4; ++j) acc[i][j] = zero;

  for (int kb = 0; kb < 16; ++kb) {
    const int k0 = kb * 32;
#pragma unroll
    for (int i = 0; i < 2; ++i) {
      const int c = (i * 4 + w) * 64 + lane;      // 16B chunk id, 0..511
      const int row = c >> 2, kk = (c & 3) * 8;
      __builtin_amdgcn_global_load_lds(AS_G(A + (size_t)(m0 + row) * 512 + k0 + kk),
                                       AS_L(As + (size_t)(i * 4 + w) * 512), 16, 0, 0);
      __builtin_amdgcn_global_load_lds(AS_G(Bt + (size_t)(n0 + row) * 512 + k0 + kk),
                                       AS_L(Bs + (size_t)(i * 4 + w) * 512), 16, 0, 0);
    }
    __syncthreads();
    bf16x8 af[4], bfr[4];
#pragma unroll
    for (int mt = 0; mt < 4; ++mt)
      af[mt] = *(const bf16x8*)(As + (wm * 64 + mt * 16 + l15) * 32 + quad * 8);
#pragma unroll
    for (int nt = 0; nt < 4; ++nt)
      bfr[nt] = *(const bf16x8*)(Bs + (wn * 64 + nt * 16 + l15) * 32 + quad * 8);
#pragma unroll
    for (int mt = 0; mt < 4; ++mt)
#pragma unroll
      for (int nt = 0; nt < 4; ++nt)
        acc[mt][nt] = __builtin_amdgcn_mfma_f32_16x16x32_bf16(af[mt], bfr[nt], acc[mt][nt], 0, 0, 0);
    __syncthreads();
  }

#pragma unroll
  for (int nt = 0; nt < 4; ++nt) {
    const int col = n0 + wn * 64 + nt * 16 + l15;
    const float bv = bias[col];
#pragma unroll
    for (int mt = 0; mt < 4; ++mt) {
      const int rowb = m0 + wm * 64 + mt * 16 + quad * 4;
#pragma unroll
      for (int r = 0; r < 4; ++r)
        C[(size_t)(rowb + r) * 4096 + col] = (__bf16)(acc[mt][nt][r] + bv);
    }
  }
}

// ---------------- persistent recurrence ----------------
// 64 blocks: dir = blk>>5, group g = blk&31 owns units u in [g*16, g*16+16).
// Lane (w, quad, l15): unit u = g*16 + w*4 + quad, batches b = l15 and l15+16.
// Swapped MFMA: D = A(U^T gatecols) x B(h cols=b) -> lane gets acc[reg] = gate
//   reg of its unit, batches l15 / l15+16: gates lane-local, no transpose.
// Sync per step kt (consumes h(kt), produces h(kt+1)):
//   wave0 polls mbox[dir][g][p] >= kt  ->  bar#1  ->  all threads load their 32
//   records ONCE, verify counter==kt (rare retry absorbs record/flag races) ->
//   stage into h_lds[kt&1] -> bar#2 (lgkm only) -> MFMA -> gates -> publish
//   records {h,kt+1} fire-and-forget -> bar#3 (issue-order only, no drains) ->
//   wave0 stores flags kt+1 fire-and-forget.
// Overwrite safety: producer publishes kt+2 (same parity as kt) only after its
//   poll of kt+1 passed, which requires OUR kt+1 flag, which is after our step-
//   kt record loads returned (data dep through compute). So counters seen at
//   step kt are only {stale kt-2/init, kt}: '== kt' is exact.

__global__ __launch_bounds__(256, 1) void k_lstm_rec(
    const __bf16* __restrict__ xg,            // [16384][4096] permuted
    const float* __restrict__ z,              // [32][512]
    const __bf16* __restrict__ UT,            // [2][2048][512] permuted
    unsigned long long* __restrict__ rbuf,    // [2][2][8192] records
    int* __restrict__ mbox,                   // [2][32][32] flags
    float* __restrict__ outf,                 // d_out [32][512][512] (fwd)
    __bf16* __restrict__ outb)                // ws [32][512][512] (bwd)
{
  const int blk = blockIdx.x, dir = blk >> 5, g = blk & 31;
  const int tid = threadIdx.x, w = tid >> 6, lane = tid & 63;
  const int quad = lane >> 4, l15 = lane & 15;
  __shared__ __align__(16) char h_lds[2][16 * 2048];   // 64 KB double buffer

  // U^T slice resident in registers for all 512 steps (64 VGPRs)
  bf16x8 breg[16];
  {
    const __bf16* up = UT + ((size_t)dir * 2048 + g * 64 + w * 16 + l15) * 512 + quad * 8;
#pragma unroll
    for (int ks = 0; ks < 16; ++ks) breg[ks] = *(const bf16x8*)(up + ks * 32);
  }

  const int u = g * 16 + w * 4 + quad;
  float c0 = z[l15 * 512 + u];
  float c1 = z[(l15 + 16) * 512 + u];

  // staging role: thread (ks_s = w*4+quad, b16 = l15) owns 32 contiguous
  // records [b16][ks_s*32 .. ks_s*32+32).
  const int ks_s = w * 4 + quad;
  const int swz = (l15 >> 1) & 3;
  unsigned long long* rb_dir = rbuf + (size_t)dir * 16384;
  const unsigned long long* src_base = rb_dir + l15 * 512 + ks_s * 32;
  const int pidx = l15 * 512 + u;
  const size_t xgoff = (size_t)dir * 2048 + g * 64 + w * 16 + quad * 4;
  const int* my_line = mbox + dir * 1024 + g * 32;         // consumer flags
  int* my_col = mbox + dir * 1024 + (lane & 31) * 32 + g;  // producer slot (wave0)

  for (int kt = 0; kt < 512; ++kt) {
    const int t = dir ? (511 - kt) : kt;
    const int pr = kt & 1;

    // xg prefetch (independent; completes under the poll)
    const bf16x4 xA = *(const bf16x4*)(xg + (size_t)(l15 * 512 + t) * 4096 + xgoff);
    const bf16x4 xB = *(const bf16x4*)(xg + (size_t)((l15 + 16) * 512 + t) * 4096 + xgoff);

    if (kt > 0) {
      if (w == 0) {
        const int* mb = my_line + (lane & 31);
        for (;;) {
          int v = __hip_atomic_load(mb, __ATOMIC_RELAXED, __HIP_MEMORY_SCOPE_AGENT);
          if (!__ballot(lane < 32 && v < kt)) break;
          __builtin_amdgcn_s_sleep(1);
        }
      }
      __syncthreads();   // bar#1: releases waves 1-3 once all producers flagged
    }

    // ---- load 32 records ONCE; counter-verify; rare retry ----
    unsigned long long rec[32];
    {
      const unsigned long long* srcp = src_base + pr * 8192;
      const unsigned expect = (unsigned)kt;
#pragma unroll
      for (int it = 0; it < 32; ++it)
        rec[it] = __hip_atomic_load(srcp + it, __ATOMIC_RELAXED,
                                    __HIP_MEMORY_SCOPE_AGENT);
      int ok = 1;
#pragma unroll
      for (int it = 0; it < 32; ++it)
        ok &= ((unsigned)(rec[it] >> 32) == expect);
      int need = !ok;
      while (__ballot(need)) {          // rare: record outran its flag
        __builtin_amdgcn_s_sleep(1);
        if (need) {
#pragma unroll
          for (int it = 0; it < 32; ++it)
            rec[it] = __hip_atomic_load(srcp + it, __ATOMIC_RELAXED,
                                        __HIP_MEMORY_SCOPE_AGENT);
          ok = 1;
#pragma unroll
          for (int it = 0; it < 32; ++it)
            ok &= ((unsigned)(rec[it] >> 32) == expect);
          need = !ok;
        }
      }
    }

    // ---- pack payloads & stage into buffer pr (conflict-free b128 writes) ----
    {
      char* base = h_lds[pr] + ks_s * 2048 + l15 * 64;
#pragma unroll
      for (int cu = 0; cu < 4; ++cu) {
        uvec4 lo, hi;
#pragma unroll
        for (int i = 0; i < 4; ++i) {
          const unsigned p0 = (unsigned)rec[cu * 8 + 2 * i];
          const unsigned p1 = (unsigned)rec[cu * 8 + 2 * i + 1];
          lo[i] = (p0 & 0xffffu) | (p1 << 16);
          hi[i] = (p0 >> 16) | (p1 & 0xffff0000u);
        }
        const int cpos = ((cu ^ swz) * 16);
        *(uvec4*)(base + cpos) = lo;           // row b16
        *(uvec4*)(base + 1024 + cpos) = hi;    // row b16+16
      }
    }
    // bar#2: staging visible (LDS-only drain; no vmem drains on critical path)
    asm volatile("s_waitcnt lgkmcnt(0)\n\ts_barrier" ::: "memory");

    fvec4 acc0 = {0.f, 0.f, 0.f, 0.f}, acc1 = {0.f, 0.f, 0.f, 0.f};
    {
      const char* rbase = h_lds[pr];
#pragma unroll 8
      for (int ks = 0; ks < 16; ++ks) {
        const char* p = rbase + ks * 2048 + l15 * 64 + ((quad ^ swz) * 16);
        bf16x8 a0 = *(const bf16x8*)p;
        bf16x8 a1 = *(const bf16x8*)(p + 1024);
        acc0 = __builtin_amdgcn_mfma_f32_16x16x32_bf16(breg[ks], a0, acc0, 0, 0, 0);
        acc1 = __builtin_amdgcn_mfma_f32_16x16x32_bf16(breg[ks], a1, acc1, 0, 0, 0);
      }
    }

    // gates are lane-local: acc[reg] = gate reg (i,f,c,o) for this lane's unit
    float ii = sigm(acc0[0] + (float)xA[0]);
    float ff = sigm(acc0[1] + (float)xA[1]);
    float cc = tanh_f(acc0[2] + (float)xA[2]);
    float oo = sigm(acc0[3] + (float)xA[3]);
    c0 = ff * c0 + ii * cc;
    const float h0 = oo * tanh_f(c0);

    ii = sigm(acc1[0] + (float)xB[0]);
    ff = sigm(acc1[1] + (float)xB[1]);
    cc = tanh_f(acc1[2] + (float)xB[2]);
    oo = sigm(acc1[3] + (float)xB[3]);
    c1 = ff * c1 + ii * cc;
    const float h1 = oo * tanh_f(c1);

    // publish record fire-and-forget: {h0,h1,kt+1}, single-copy-atomic 8B
    union { __bf16 h[2]; unsigned u32; } pk;
    pk.h[0] = (__bf16)h0;
    pk.h[1] = (__bf16)h1;
    const unsigned long long rv =
        (unsigned long long)pk.u32 | ((unsigned long long)(unsigned)(kt + 1) << 32);
    __hip_atomic_store(rb_dir + ((kt + 1) & 1) * 8192 + pidx, rv,
                       __ATOMIC_RELAXED, __HIP_MEMORY_SCOPE_AGENT);

    // bar#3: issue-order alignment only (no waitcnt) — all waves' record stores
    // are issued before wave0 flags; any fabric reorder is counter-absorbed.
    asm volatile("s_barrier" ::: "memory");
    if (w == 0 && lane < 32)
      __hip_atomic_store(my_col, kt + 1, __ATOMIC_RELAXED, __HIP_MEMORY_SCOPE_AGENT);

    // out stores off the critical path
    const size_t o0 = (size_t)(l15 * 512 + t) * 512 + u;
    const size_t o1 = (size_t)((l15 + 16) * 512 + t) * 512 + u;
    if (dir == 0) {
      outf[o0] = h0;
      outf[o1] = h1;
    } else {
      outb[o0] = (__bf16)h0;
      outb[o1] = (__bf16)h1;
    }
  }
}

// ---------------- final merge ----------------

__global__ void k_add_bwd(float* __restrict__ out, const __bf16* __restrict__ outb) {
  size_t i = ((size_t)blockIdx.x * 256 + threadIdx.x) * 4;
  if (i >= (size_t)32 * 512 * 512) return;
  fvec4 o = *(const fvec4*)(out + i);
  bf16x4 bv = *(const bf16x4*)(outb + i);
#pragma unroll
  for (int j = 0; j < 4; ++j) o[j] += (float)bv[j];
  *(fvec4*)(out + i) = o;
}

// ---------------- host ----------------

extern "C" void kernel_launch(void* const* d_in, const int* in_sizes, int n_in,
                              void* d_out, int out_size, void* d_ws, size_t ws_size,
                              hipStream_t stream) {
  const float* x  = (const float*)d_in[0];
  const float* z  = (const float*)d_in[1];
  const float* Wf = (const float*)d_in[2];
  const float* Uf = (const float*)d_in[3];
  const float* bf = (const float*)d_in[4];
  const float* Wb = (const float*)d_in[5];
  const float* Ub = (const float*)d_in[6];
  const float* bb = (const float*)d_in[7];
  float* out = (float*)d_out;
  char* ws = (char*)d_ws;

  size_t off = 0;
  __bf16* xg = (__bf16*)(ws + off); off += (size_t)16384 * 4096 * 2;   // 134 MB
  __bf16* UT = (__bf16*)(ws + off); off += (size_t)2 * 2048 * 512 * 2; // 4 MB
  unsigned long long* rbuf = (unsigned long long*)(ws + off);
  off += (size_t)2 * 2 * 8192 * 8;                                     // 256 KB
  int* mbox = (int*)(ws + off); off += 8192;                           // 2*32*32 ints
  float* biasp = (float*)(ws + off); off += 4096 * 4;
  char* uni = ws + off;
  __bf16* xb   = (__bf16*)uni;                               // phase 1
  __bf16* WT   = (__bf16*)(uni + (size_t)16384 * 512 * 2);   // phase 1
  __bf16* outb = (__bf16*)uni;                               // phase 2 (aliases xb)

  k_convert_x<<<4096, 256, 0, stream>>>(x, xb);
  k_build_T<<<2048, 256, 0, stream>>>(Wf, bf, WT, biasp);
  k_build_T<<<2048, 256, 0, stream>>>(Wb, bb, WT + (size_t)2048 * 512, biasp + 2048);
  k_build_T<<<2048, 256, 0, stream>>>(Uf, nullptr, UT, nullptr);
  k_build_T<<<2048, 256, 0, stream>>>(Ub, nullptr, UT + (size_t)2048 * 512, nullptr);
  k_init_rec<<<128, 256, 0, stream>>>(z, rbuf);
  k_init_flags<<<8, 256, 0, stream>>>(mbox);
  k_gemm_xw<<<dim3(32, 128), 256, 0, stream>>>(xb, WT, biasp, xg);
  k_lstm_rec<<<64, 256, 0, stream>>>(xg, z, UT, rbuf, mbox, out, outb);
  k_add_bwd<<<8192, 256, 0, stream>>>(out, outb);
}

// Round 5
// 2762.400 us; speedup vs baseline: 2.1937x; 1.5852x over previous
//
#include <hip/hip_runtime.h>
#include <hip/hip_bf16.h>

// Bidirectional LSTM, B=32 T=512 D=512 U=512, fp32 in/out, bf16 MFMA internals.
// Phase 1: xg = x @ [Wf||Wb] + b  (bf16 MFMA GEMM, permuted columns)
// Phase 2: persistent recurrence, 32 groups/direction, U^T in registers.
//          R9 = R5 flag-after-ack protocol + R7 swapped-MFMA core, with the
//          data plane rebuilt for per-INSTRUCTION lane coalescing (the R8
//          lesson: agent-scope traffic bypasses L1/L2, so only instruction-
//          level coalescing exists):
//          - exchange: [ks][b16][u'] 4B pairs {h[b],h[b+16]} -> producer one
//            4B store; consumer 16x8B loads, 512B contiguous per wave instr
//          - per-wave flags + all-wave coalesced polling -> ONE barrier/step
//          - LDS chunk-XOR swizzle (R7, 0 conflicts), lane-local gates
// Phase 3: out = fwd + bwd

typedef __attribute__((ext_vector_type(8))) __bf16 bf16x8;
typedef __attribute__((ext_vector_type(4))) __bf16 bf16x4;
typedef __attribute__((ext_vector_type(4))) float fvec4;

#define AS_G(p) ((const __attribute__((address_space(1))) void*)(p))
#define AS_L(p) ((__attribute__((address_space(3))) void*)(p))

__device__ __forceinline__ float sigm(float x) {
  return __builtin_amdgcn_rcpf(1.f + __expf(-x));
}
__device__ __forceinline__ float tanh_f(float x) {
  return 1.f - 2.f * __builtin_amdgcn_rcpf(__expf(2.f * x) + 1.f);
}

// ---------------- conversions ----------------

__global__ void k_convert_x(const float* __restrict__ x, __bf16* __restrict__ xb) {
  size_t i = ((size_t)blockIdx.x * 256 + threadIdx.x) * 8;
  fvec4 a = *(const fvec4*)(x + i);
  fvec4 b = *(const fvec4*)(x + i + 4);
  bf16x8 o;
#pragma unroll
  for (int j = 0; j < 4; ++j) { o[j] = (__bf16)a[j]; o[4 + j] = (__bf16)b[j]; }
  *(bf16x8*)(xb + i) = o;
}

// dst[p][k] = src[k][orig(p)] as bf16. Permutation: p = g*64 + w*16 + jj*4 + gate
// <-> orig = gate*512 + g*16 + w*4 + jj  (Keras gate order i,f,c,o).
__global__ void k_build_T(const float* __restrict__ src, const float* __restrict__ bvec,
                          __bf16* __restrict__ dst, float* __restrict__ bias_out) {
  int p = blockIdx.x;
  int g = p >> 6, r = p & 63, w = r >> 4, q = r & 15, jj = q >> 2, gate = q & 3;
  int orig = gate * 512 + g * 16 + w * 4 + jj;
  for (int k = threadIdx.x; k < 512; k += 256)
    dst[(size_t)p * 512 + k] = (__bf16)src[(size_t)k * 2048 + orig];
  if (bias_out && threadIdx.x == 0) bias_out[p] = bvec[orig];
}

// init parity-0 h buffers from z: hbuf[dir][par 0][ks 16][b16 16][u' 32] 4B pairs
__global__ void k_init_h(const float* __restrict__ z, unsigned int* __restrict__ hbuf) {
  int idx = blockIdx.x * 256 + threadIdx.x;      // 0..16383
  int dir = idx >> 13, rem = idx & 8191;
  int ks = rem >> 9, b16 = (rem >> 5) & 15, u2 = rem & 31;
  int uu = ks * 32 + u2;
  union { __bf16 h[2]; unsigned u32; } pk;
  pk.h[0] = (__bf16)z[b16 * 512 + uu];
  pk.h[1] = (__bf16)z[(b16 + 16) * 512 + uu];
  hbuf[(size_t)dir * 16384 + rem] = pk.u32;      // parity 0 region
}

// zero the flag region: 2 dirs * 32 consumers * 128 producer-waves ints
__global__ void k_init_flags(int* mbox) {
  int i = blockIdx.x * 256 + threadIdx.x;
  if (i < 8192) mbox[i] = 0;
}

// ---------------- input GEMM: [16384,512] x [4096,512]^T -> bf16 [16384,4096] ----------------

__global__ __launch_bounds__(256, 2) void k_gemm_xw(
    const __bf16* __restrict__ A,   // [16384][512] bf16
    const __bf16* __restrict__ Bt,  // [4096][512] bf16 (permuted W^T)
    const float* __restrict__ bias, // [4096] permuted
    __bf16* __restrict__ C)         // [16384][4096]
{
  __shared__ __align__(16) __bf16 As[128 * 32];
  __shared__ __align__(16) __bf16 Bs[128 * 32];
  const int tid = threadIdx.x;
  const int w = tid >> 6, lane = tid & 63, quad = lane >> 4, l15 = lane & 15;
  const int m0 = blockIdx.y * 128, n0 = blockIdx.x * 128;
  const int wm = w & 1, wn = w >> 1;

  fvec4 acc[4][4];
  const fvec4 zero = {0.f, 0.f, 0.f, 0.f};
#pragma unroll
  for (int i = 0; i < 4; ++i)
#pragma unroll
    for (int j = 0; j < 4; ++j) acc[i][j] = zero;

  for (int kb = 0; kb < 16; ++kb) {
    const int k0 = kb * 32;
#pragma unroll
    for (int i = 0; i < 2; ++i) {
      const int c = (i * 4 + w) * 64 + lane;      // 16B chunk id, 0..511
      const int row = c >> 2, kk = (c & 3) * 8;
      __builtin_amdgcn_global_load_lds(AS_G(A + (size_t)(m0 + row) * 512 + k0 + kk),
                                       AS_L(As + (size_t)(i * 4 + w) * 512), 16, 0, 0);
      __builtin_amdgcn_global_load_lds(AS_G(Bt + (size_t)(n0 + row) * 512 + k0 + kk),
                                       AS_L(Bs + (size_t)(i * 4 + w) * 512), 16, 0, 0);
    }
    __syncthreads();
    bf16x8 af[4], bfr[4];
#pragma unroll
    for (int mt = 0; mt < 4; ++mt)
      af[mt] = *(const bf16x8*)(As + (wm * 64 + mt * 16 + l15) * 32 + quad * 8);
#pragma unroll
    for (int nt = 0; nt < 4; ++nt)
      bfr[nt] = *(const bf16x8*)(Bs + (wn * 64 + nt * 16 + l15) * 32 + quad * 8);
#pragma unroll
    for (int mt = 0; mt < 4; ++mt)
#pragma unroll
      for (int nt = 0; nt < 4; ++nt)
        acc[mt][nt] = __builtin_amdgcn_mfma_f32_16x16x32_bf16(af[mt], bfr[nt], acc[mt][nt], 0, 0, 0);
    __syncthreads();
  }

#pragma unroll
  for (int nt = 0; nt < 4; ++nt) {
    const int col = n0 + wn * 64 + nt * 16 + l15;
    const float bv = bias[col];
#pragma unroll
    for (int mt = 0; mt < 4; ++mt) {
      const int rowb = m0 + wm * 64 + mt * 16 + quad * 4;
#pragma unroll
      for (int r = 0; r < 4; ++r)
        C[(size_t)(rowb + r) * 4096 + col] = (__bf16)(acc[mt][nt][r] + bv);
    }
  }
}

// ---------------- persistent recurrence ----------------
// 64 blocks: dir = blk>>5, group g = blk&31 owns units u in [g*16, g*16+16).
// Lane (w, quad, l15): unit u = g*16 + w*4 + quad, batches b = l15 and l15+16.
// Swapped MFMA: D = A(U^T gatecols) x B(h cols=b) -> acc[reg] = gate reg of the
//   lane's unit for its two batches: gates lane-local, no transpose.
// hbuf[dir][par][ks 16][b16 16][u' 32] 4B pairs {h[b16][u], h[b16+16][u]}.
//   Producer: ONE 4B agent store. Consumer thread t: (b16 = t>>4, u' = 2(t&15)),
//   16 loads of 8B at dword 2t + ks*512: per wave instr = 512B contiguous.
// Flags mbox[dir][consumer 32][pw 128]: producer-wave pw = g*4+w stores kt+1
//   AFTER its own vmcnt(0) (publish acked at IC) -> consumer needs no verify.
//   Consumers: all 4 waves poll; lane reads flags (2*lane, 2*lane+1) as one 8B.
// ONE barrier/step (staging visibility). Double-buffered h_lds: a wave's frag
//   reads of buf p drain (lgkmcnt) at its NEXT barrier entry, and buf p is only
//   overwritten at kt+2, after ALL waves passed the kt+1 barrier -> WAR safe.
// Overwrite-vs-read safety: wave publishes h(kt+2) into par p only after its
//   poll(kt+1) saw all flags >= kt+1; any flag kt+1 is program-ordered after
//   that wave's staging loads of h(kt) completed -> no lost updates.

__global__ __launch_bounds__(256, 1) void k_lstm_rec(
    const __bf16* __restrict__ xg,            // [16384][4096] permuted
    const float* __restrict__ z,              // [32][512]
    const __bf16* __restrict__ UT,            // [2][2048][512] permuted
    unsigned int* __restrict__ hbuf,          // [2][2][8192] 4B pairs
    int* __restrict__ mbox,                   // [2][32][128] flags
    float* __restrict__ outf,                 // d_out [32][512][512] (fwd)
    __bf16* __restrict__ outb)                // ws [32][512][512] (bwd)
{
  const int blk = blockIdx.x, dir = blk >> 5, g = blk & 31;
  const int tid = threadIdx.x, w = tid >> 6, lane = tid & 63;
  const int quad = lane >> 4, l15 = lane & 15;
  __shared__ __align__(16) char h_lds[2][16 * 2048];   // 64 KB double buffer

  // U^T slice resident in registers for all 512 steps (64 VGPRs)
  bf16x8 breg[16];
  {
    const __bf16* up = UT + ((size_t)dir * 2048 + g * 64 + w * 16 + l15) * 512 + quad * 8;
#pragma unroll
    for (int ks = 0; ks < 16; ++ks) breg[ks] = *(const bf16x8*)(up + ks * 32);
  }

  const int u = g * 16 + w * 4 + quad;
  float c0 = z[l15 * 512 + u];
  float c1 = z[(l15 + 16) * 512 + u];

  // staging mapping: thread t owns (b16 = t>>4, units u' = 2(t&15), 2(t&15)+1)
  const int b16s = tid >> 4, upair = (tid & 15) * 2;
  const int swz_s = (b16s >> 1) & 3;
  const int off0 = b16s * 64 + (((upair >> 3) ^ swz_s) * 16) + (upair & 7) * 2;
  // fragment read mapping (R7-proven, 0 conflicts)
  const int swz_f = (l15 >> 1) & 3;
  const int foff = l15 * 64 + ((quad ^ swz_f) * 16);

  unsigned int* hb = hbuf + (size_t)dir * 16384;          // [par][8192]
  const int pidx = (g >> 1) * 512 + l15 * 32 + (g & 1) * 16 + w * 4 + quad;
  const size_t xgoff = (size_t)dir * 2048 + g * 64 + w * 16 + quad * 4;
  const unsigned long long* flagp =
      (const unsigned long long*)(mbox + (dir * 32 + g) * 128) + lane;
  int* fstore = mbox + (dir * 32 + (lane & 31)) * 128 + g * 4 + w;   // lane<32

  for (int kt = 0; kt < 512; ++kt) {
    const int t = dir ? (511 - kt) : kt;
    const int pr = kt & 1;

    // xg prefetch (independent; completes under the poll)
    const bf16x4 xA = *(const bf16x4*)(xg + (size_t)(l15 * 512 + t) * 4096 + xgoff);
    const bf16x4 xB = *(const bf16x4*)(xg + (size_t)((l15 + 16) * 512 + t) * 4096 + xgoff);

    if (kt > 0) {
      for (;;) {
        unsigned long long f = __hip_atomic_load(flagp, __ATOMIC_RELAXED,
                                                 __HIP_MEMORY_SCOPE_AGENT);
        if (!__ballot((int)(f & 0xffffffffu) < kt || (int)(f >> 32) < kt)) break;
        __builtin_amdgcn_s_sleep(1);
      }
      asm volatile("" ::: "memory");   // no staging load crosses above the poll
    }

    // ---- staging: 16 x 8B loads, 512B contiguous per wave instruction ----
    {
      const unsigned long long* srcp =
          (const unsigned long long*)(hb + pr * 8192) + tid;
      unsigned long long rec[16];
#pragma unroll
      for (int i = 0; i < 16; ++i)
        rec[i] = __hip_atomic_load(srcp + i * 256, __ATOMIC_RELAXED,
                                   __HIP_MEMORY_SCOPE_AGENT);
      char* dst = h_lds[pr];
#pragma unroll
      for (int i = 0; i < 16; ++i) {
        const unsigned d0 = (unsigned)rec[i], d1 = (unsigned)(rec[i] >> 32);
        *(unsigned*)(dst + i * 2048 + off0) = (d0 & 0xffffu) | (d1 << 16);
        *(unsigned*)(dst + i * 2048 + off0 + 1024) = (d0 >> 16) | (d1 & 0xffff0000u);
      }
    }
    // the ONE barrier per step: staging visible to all waves
    asm volatile("s_waitcnt lgkmcnt(0)\n\ts_barrier" ::: "memory");

    fvec4 acc0 = {0.f, 0.f, 0.f, 0.f}, acc1 = {0.f, 0.f, 0.f, 0.f};
    {
      const char* rb = h_lds[pr];
#pragma unroll 8
      for (int ks = 0; ks < 16; ++ks) {
        bf16x8 a0 = *(const bf16x8*)(rb + ks * 2048 + foff);
        bf16x8 a1 = *(const bf16x8*)(rb + ks * 2048 + 1024 + foff);
        acc0 = __builtin_amdgcn_mfma_f32_16x16x32_bf16(breg[ks], a0, acc0, 0, 0, 0);
        acc1 = __builtin_amdgcn_mfma_f32_16x16x32_bf16(breg[ks], a1, acc1, 0, 0, 0);
      }
    }

    // gates are lane-local: acc[reg] = gate reg (i,f,c,o) for this lane's unit
    float ii = sigm(acc0[0] + (float)xA[0]);
    float ff = sigm(acc0[1] + (float)xA[1]);
    float cc = tanh_f(acc0[2] + (float)xA[2]);
    float oo = sigm(acc0[3] + (float)xA[3]);
    c0 = ff * c0 + ii * cc;
    const float h0 = oo * tanh_f(c0);

    ii = sigm(acc1[0] + (float)xB[0]);
    ff = sigm(acc1[1] + (float)xB[1]);
    cc = tanh_f(acc1[2] + (float)xB[2]);
    oo = sigm(acc1[3] + (float)xB[3]);
    c1 = ff * c1 + ii * cc;
    const float h1 = oo * tanh_f(c1);

    // publish h pair: one 4B agent store into next parity buffer
    union { __bf16 h[2]; unsigned u32; } pk;
    pk.h[0] = (__bf16)h0;
    pk.h[1] = (__bf16)h1;
    __hip_atomic_store(hb + ((kt + 1) & 1) * 8192 + pidx, pk.u32,
                       __ATOMIC_RELAXED, __HIP_MEMORY_SCOPE_AGENT);
    // per-wave ack drain: only this wave's publish is still outstanding here
    asm volatile("s_waitcnt vmcnt(0)" ::: "memory");
    if (lane < 32)
      __hip_atomic_store(fstore, kt + 1, __ATOMIC_RELAXED, __HIP_MEMORY_SCOPE_AGENT);

    // out stores off the critical path (retire during next step's poll)
    const size_t o0 = (size_t)(l15 * 512 + t) * 512 + u;
    const size_t o1 = (size_t)((l15 + 16) * 512 + t) * 512 + u;
    if (dir == 0) {
      outf[o0] = h0;
      outf[o1] = h1;
    } else {
      outb[o0] = (__bf16)h0;
      outb[o1] = (__bf16)h1;
    }
  }
}

// ---------------- final merge ----------------

__global__ void k_add_bwd(float* __restrict__ out, const __bf16* __restrict__ outb) {
  size_t i = ((size_t)blockIdx.x * 256 + threadIdx.x) * 4;
  if (i >= (size_t)32 * 512 * 512) return;
  fvec4 o = *(const fvec4*)(out + i);
  bf16x4 bv = *(const bf16x4*)(outb + i);
#pragma unroll
  for (int j = 0; j < 4; ++j) o[j] += (float)bv[j];
  *(fvec4*)(out + i) = o;
}

// ---------------- host ----------------

extern "C" void kernel_launch(void* const* d_in, const int* in_sizes, int n_in,
                              void* d_out, int out_size, void* d_ws, size_t ws_size,
                              hipStream_t stream) {
  const float* x  = (const float*)d_in[0];
  const float* z  = (const float*)d_in[1];
  const float* Wf = (const float*)d_in[2];
  const float* Uf = (const float*)d_in[3];
  const float* bf = (const float*)d_in[4];
  const float* Wb = (const float*)d_in[5];
  const float* Ub = (const float*)d_in[6];
  const float* bb = (const float*)d_in[7];
  float* out = (float*)d_out;
  char* ws = (char*)d_ws;

  size_t off = 0;
  __bf16* xg = (__bf16*)(ws + off); off += (size_t)16384 * 4096 * 2;   // 134 MB
  __bf16* UT = (__bf16*)(ws + off); off += (size_t)2 * 2048 * 512 * 2; // 4 MB
  unsigned int* hbuf = (unsigned int*)(ws + off);
  off += (size_t)2 * 2 * 8192 * 4;                                     // 128 KB
  int* mbox = (int*)(ws + off); off += (size_t)2 * 32 * 128 * 4;       // 32 KB
  float* biasp = (float*)(ws + off); off += 4096 * 4;
  char* uni = ws + off;
  __bf16* xb   = (__bf16*)uni;                               // phase 1
  __bf16* WT   = (__bf16*)(uni + (size_t)16384 * 512 * 2);   // phase 1
  __bf16* outb = (__bf16*)uni;                               // phase 2 (aliases xb)

  k_convert_x<<<4096, 256, 0, stream>>>(x, xb);
  k_build_T<<<2048, 256, 0, stream>>>(Wf, bf, WT, biasp);
  k_build_T<<<2048, 256, 0, stream>>>(Wb, bb, WT + (size_t)2048 * 512, biasp + 2048);
  k_build_T<<<2048, 256, 0, stream>>>(Uf, nullptr, UT, nullptr);
  k_build_T<<<2048, 256, 0, stream>>>(Ub, nullptr, UT + (size_t)2048 * 512, nullptr);
  k_init_h<<<64, 256, 0, stream>>>(z, hbuf);
  k_init_flags<<<32, 256, 0, stream>>>(mbox);
  k_gemm_xw<<<dim3(32, 128), 256, 0, stream>>>(xb, WT, biasp, xg);
  k_lstm_rec<<<64, 256, 0, stream>>>(xg, z, UT, hbuf, mbox, out, outb);
  k_add_bwd<<<8192, 256, 0, stream>>>(out, outb);
}